// Round 2
// baseline (1144.780 us; speedup 1.0000x reference)
//
#include <hip/hip_runtime.h>
#include <math.h>

#define NTOK 100000
#define C 1024
#define SN 18
#define H 4
#define DH 256
#define HSN 72
#define CLAMPV 10000.0f
#define EPSV 1e-8f

using short8 = __attribute__((ext_vector_type(8))) short;
using f32x4  = __attribute__((ext_vector_type(4))) float;

union S8u { unsigned short u[8]; short8 v; };

__device__ __forceinline__ float sanitize_f(float v) {
    if (isnan(v)) return 0.0f;
    return fminf(CLAMPV, fmaxf(-CLAMPV, v));
}
__device__ __forceinline__ unsigned short f2bf(float f) {
    unsigned int u = __float_as_uint(f);
    u = (u + 0x7FFFu + ((u >> 16) & 1u)) >> 16;
    return (unsigned short)u;
}
__device__ __forceinline__ float waveSum(float v) {
    #pragma unroll
    for (int o = 32; o > 0; o >>= 1) v += __shfl_down(v, o, 64);
    return v;
}
__device__ __forceinline__ float waveMax(float v) {
    #pragma unroll
    for (int o = 32; o > 0; o >>= 1) v = fmaxf(v, __shfl_down(v, o, 64));
    return v;
}

// q = rmsnorm(seeds, w_nq); one block per seed row
__global__ void k_qnorm(const float* __restrict__ seeds, const float* __restrict__ w_nq,
                        float* __restrict__ q) {
    int row = blockIdx.x, tid = threadIdx.x;
    const float* src = seeds + (size_t)row * C;
    float ss = 0.f;
    for (int c = tid; c < C; c += 256) { float v = sanitize_f(src[c]); ss += v * v; }
    __shared__ float red[4]; __shared__ float sSc;
    float w = waveSum(ss);
    if ((tid & 63) == 0) red[tid >> 6] = w;
    __syncthreads();
    if (tid == 0) {
        float t = red[0] + red[1] + red[2] + red[3];
        float rms = sqrtf(t / (float)C);
        sSc = 1.0f / (rms + EPSV);
    }
    __syncthreads();
    float sc = sSc;
    for (int c = tid; c < C; c += 256) q[(size_t)row * C + c] = w_nq[c] * sanitize_f(src[c]) * sc;
}

// qp[s][j] = (q[s]·Wq[j] + bq[j]) / sqrt(Dh); one wave per output
__global__ void k_qp(const float* __restrict__ q, const float* __restrict__ Wq,
                     const float* __restrict__ bq, float* __restrict__ qp) {
    int tid = threadIdx.x, wid = tid >> 6, lane = tid & 63;
    int out = blockIdx.x * 4 + wid;          // < 18432
    int s = out >> 10, j = out & 1023;
    const float* qrow = q + (size_t)s * C;
    const float* wrow = Wq + (size_t)j * C;
    float acc = 0.f;
    #pragma unroll
    for (int k = 0; k < 16; ++k) { int c = lane + 64 * k; acc = fmaf(qrow[c], wrow[c], acc); }
    acc = waveSum(acc);
    if (lane == 0) qp[out] = (acc + bq[j]) * 0.0625f;
}

// Ub[row][c] = bf16( (sum_d qp[s][h*DH+d] * Wk[h*DH+d][c]) * w_nkv[c] );  row = h*SN+s, rows 72..79 = 0
// bsc[row] (= qp[s,h,:]·bk[h,:]) folded in: computed by the ct==0 block of each row.
__global__ void k_U(const float* __restrict__ qp, const float* __restrict__ in_proj_w,
                    const float* __restrict__ in_proj_b, const float* __restrict__ w_nkv,
                    unsigned short* __restrict__ Ub, float* __restrict__ bsc) {
    int b = blockIdx.x, tid = threadIdx.x;
    int row = b >> 2, ct = b & 3;
    int c = ct * 256 + tid;
    __shared__ float qps[DH];
    __shared__ float red2[4];
    if (row < HSN) {
        int h = row / SN, s = row % SN;
        qps[tid] = qp[(size_t)s * C + h * DH + tid];
        __syncthreads();
        if (ct == 0) {                               // block-uniform branch
            float pb = qps[tid] * in_proj_b[C + h * DH + tid];
            float wsum = waveSum(pb);
            if ((tid & 63) == 0) red2[tid >> 6] = wsum;
            __syncthreads();
            if (tid == 0) bsc[row] = red2[0] + red2[1] + red2[2] + red2[3];
        }
        const float* Wk = in_proj_w + (size_t)C * C;
        float acc = 0.f;
        #pragma unroll 4
        for (int d = 0; d < DH; ++d) acc = fmaf(qps[d], Wk[(size_t)(h * DH + d) * C + c], acc);
        Ub[(size_t)row * C + c] = f2bf(acc * w_nkv[c]);
    } else {
        Ub[(size_t)row * C + c] = 0;
    }
}

// x fragment prefetch: DST_[nt][ks][half], pointers xr0/xr1 already include q*8
#define LOADX(DST_, KT_) { \
    DST_[0][0][0] = *(const float4*)(xr0 + (KT_) * 64);      \
    DST_[0][0][1] = *(const float4*)(xr0 + (KT_) * 64 + 4);  \
    DST_[0][1][0] = *(const float4*)(xr0 + (KT_) * 64 + 32); \
    DST_[0][1][1] = *(const float4*)(xr0 + (KT_) * 64 + 36); \
    DST_[1][0][0] = *(const float4*)(xr1 + (KT_) * 64);      \
    DST_[1][0][1] = *(const float4*)(xr1 + (KT_) * 64 + 4);  \
    DST_[1][1][0] = *(const float4*)(xr1 + (KT_) * 64 + 32); \
    DST_[1][1][1] = *(const float4*)(xr1 + (KT_) * 64 + 36); }

#define PACK4(VV, SSV, DST, I0) { \
    float v0_ = sanitize_f((VV).x), v1_ = sanitize_f((VV).y); \
    float v2_ = sanitize_f((VV).z), v3_ = sanitize_f((VV).w); \
    SSV += v0_ * v0_ + v1_ * v1_ + v2_ * v2_ + v3_ * v3_; \
    DST.u[I0]     = f2bf(v0_); DST.u[I0 + 1] = f2bf(v1_); \
    DST.u[I0 + 2] = f2bf(v2_); DST.u[I0 + 3] = f2bf(v3_); }

#define CONVSTORE(XB_, KT_) { \
    S8u t00, t01, t10, t11; \
    PACK4(XB_[0][0][0], ss0, t00, 0); PACK4(XB_[0][0][1], ss0, t00, 4); \
    PACK4(XB_[0][1][0], ss0, t01, 0); PACK4(XB_[0][1][1], ss0, t01, 4); \
    PACK4(XB_[1][0][0], ss1, t10, 0); PACK4(XB_[1][0][1], ss1, t10, 4); \
    PACK4(XB_[1][1][0], ss1, t11, 0); PACK4(XB_[1][1][1], ss1, t11, 4); \
    b[0][0] = t00.v; b[0][1] = t01.v; b[1][0] = t10.v; b[1][1] = t11.v; \
    if (writeXb) { \
        if (n_0 < NTOK) { \
            *(short8*)(xbG + (size_t)n_0 * C + (KT_) * 64 + q * 8)      = t00.v; \
            *(short8*)(xbG + (size_t)n_0 * C + (KT_) * 64 + 32 + q * 8) = t01.v; } \
        if (n_1 < NTOK) { \
            *(short8*)(xbG + (size_t)n_1 * C + (KT_) * 64 + q * 8)      = t10.v; \
            *(short8*)(xbG + (size_t)n_1 * C + (KT_) * 64 + 32 + q * 8) = t11.v; } } }

// Pass A (MFMA): scores[hs][n] = scale_n * (U[hs]·x_san[n]) + bsc[hs]
// Barrier-free: direct global->register fragment loads, no LDS.
__global__ __launch_bounds__(256, 2) void k_passA(const float* __restrict__ x,
    const unsigned short* __restrict__ Ub, const float* __restrict__ bsc,
    float* __restrict__ scaleG, float* __restrict__ scoresG,
    unsigned short* __restrict__ xbG, int writeXb) {
    int tid = threadIdx.x;
    int n0 = blockIdx.x * 128;
    int lane = tid & 63, wv = tid >> 6;
    int q = lane >> 4, mn = lane & 15;

    int n_0 = n0 + wv * 32 + mn;        // nt=0 token
    int n_1 = n_0 + 16;                 // nt=1 token
    int nc0 = n_0 < NTOK ? n_0 : NTOK - 1;   // clamp for safe loads; stores guarded
    int nc1 = n_1 < NTOK ? n_1 : NTOK - 1;
    const float* xr0 = x + (size_t)nc0 * C + q * 8;
    const float* xr1 = x + (size_t)nc1 * C + q * 8;
    const unsigned short* ubase = Ub + (size_t)mn * C + q * 8;

    f32x4 acc[5][2];
    #pragma unroll
    for (int mt = 0; mt < 5; ++mt)
        #pragma unroll
        for (int nt = 0; nt < 2; ++nt) acc[mt][nt] = (f32x4){0.f, 0.f, 0.f, 0.f};
    float ss0 = 0.f, ss1 = 0.f;

    float4 xA[2][2][2], xB[2][2][2];
    LOADX(xA, 0);
    #pragma unroll
    for (int kt = 0; kt < 16; ++kt) {
        short8 a[5][2];
        #pragma unroll
        for (int mt = 0; mt < 5; ++mt) {
            a[mt][0] = *(const short8*)(ubase + (size_t)mt * 16 * C + kt * 64);
            a[mt][1] = *(const short8*)(ubase + (size_t)mt * 16 * C + kt * 64 + 32);
        }
        short8 b[2][2];
        if ((kt & 1) == 0) {
            if (kt < 15) LOADX(xB, kt + 1);
            CONVSTORE(xA, kt);
        } else {
            if (kt < 15) LOADX(xA, kt + 1);
            CONVSTORE(xB, kt);
        }
        #pragma unroll
        for (int ks = 0; ks < 2; ++ks)
            #pragma unroll
            for (int mt = 0; mt < 5; ++mt)
                #pragma unroll
                for (int nt = 0; nt < 2; ++nt)
                    acc[mt][nt] = __builtin_amdgcn_mfma_f32_16x16x32_bf16(a[mt][ks], b[nt][ks], acc[mt][nt], 0, 0, 0);
    }

    // RMS scale: lanes differing only in q hold the same tokens
    ss0 += __shfl_xor(ss0, 16, 64); ss0 += __shfl_xor(ss0, 32, 64);
    ss1 += __shfl_xor(ss1, 16, 64); ss1 += __shfl_xor(ss1, 32, 64);
    float sc0 = 1.0f / (sqrtf(ss0 * (1.0f / (float)C)) + EPSV);
    float sc1 = 1.0f / (sqrtf(ss1 * (1.0f / (float)C)) + EPSV);
    if (q == 0) {
        if (n_0 < NTOK) scaleG[n_0] = sc0;
        if (n_1 < NTOK) scaleG[n_1] = sc1;
    }
    #pragma unroll
    for (int mt = 0; mt < 5; ++mt) {
        #pragma unroll
        for (int r = 0; r < 4; ++r) {
            int hs = mt * 16 + q * 4 + r;
            if (hs < HSN) {
                float bb = bsc[hs];
                if (n_0 < NTOK) scoresG[(size_t)hs * NTOK + n_0] = acc[mt][0][r] * sc0 + bb;
                if (n_1 < NTOK) scoresG[(size_t)hs * NTOK + n_1] = acc[mt][1][r] * sc1 + bb;
            }
        }
    }
}

// softmax stats stage 1: per (hs, chunk-of-6272): partial max + partial sum-exp (float4)
__global__ void k_stats1(const float* __restrict__ scoresG, float* __restrict__ pm,
                         float* __restrict__ pd) {
    int ch = blockIdx.x, hs = blockIdx.y, tid = threadIdx.x;
    int nbeg = ch * 6272, nend = nbeg + 6272;
    if (nend > NTOK) nend = NTOK;
    const float* row = scoresG + (size_t)hs * NTOK;
    float m = -INFINITY;
    for (int n = nbeg + 4 * tid; n < nend; n += 1024) {
        float4 v = *(const float4*)(row + n);
        m = fmaxf(fmaxf(m, fmaxf(v.x, v.y)), fmaxf(v.z, v.w));
    }
    __shared__ float red[4]; __shared__ float sM;
    float w = waveMax(m);
    if ((tid & 63) == 0) red[tid >> 6] = w;
    __syncthreads();
    if (tid == 0) sM = fmaxf(fmaxf(red[0], red[1]), fmaxf(red[2], red[3]));
    __syncthreads();
    float mm = sM;
    float sum = 0.f;
    for (int n = nbeg + 4 * tid; n < nend; n += 1024) {
        float4 v = *(const float4*)(row + n);
        sum += __expf(v.x - mm) + __expf(v.y - mm) + __expf(v.z - mm) + __expf(v.w - mm);
    }
    __syncthreads();
    float ws2 = waveSum(sum);
    if ((tid & 63) == 0) red[tid >> 6] = ws2;
    __syncthreads();
    if (tid == 0) { pm[hs * 16 + ch] = mm; pd[hs * 16 + ch] = red[0] + red[1] + red[2] + red[3]; }
}

// w-precompute (stats stage 2 folded): wb[hs][n] = bf16( exp(s-m)*scale_n/den )
__global__ void k_w(const float* __restrict__ scoresG, const float* __restrict__ pm,
                    const float* __restrict__ pd, const float* __restrict__ scaleG,
                    unsigned short* __restrict__ wb) {
    int hs = blockIdx.y;
    __shared__ float sM, sI;
    if (threadIdx.x == 0) {
        float m = -INFINITY;
        #pragma unroll
        for (int i = 0; i < 16; ++i) m = fmaxf(m, pm[hs * 16 + i]);
        float s = 0.f;
        #pragma unroll
        for (int i = 0; i < 16; ++i) s += pd[hs * 16 + i] * __expf(pm[hs * 16 + i] - m);
        sM = m; sI = 1.0f / s;
    }
    __syncthreads();
    int n = (blockIdx.x * 256 + threadIdx.x) * 4;
    if (n >= NTOK) return;
    float mh = sM, ih = sI;
    float4 s4 = *(const float4*)(scoresG + (size_t)hs * NTOK + n);
    float4 c4 = *(const float4*)(scaleG + n);
    unsigned int lo = (unsigned int)f2bf(__expf(s4.x - mh) * c4.x * ih)
                    | ((unsigned int)f2bf(__expf(s4.y - mh) * c4.y * ih) << 16);
    unsigned int hi = (unsigned int)f2bf(__expf(s4.z - mh) * c4.z * ih)
                    | ((unsigned int)f2bf(__expf(s4.w - mh) * c4.w * ih) << 16);
    *(uint2*)&wb[(size_t)hs * NTOK + n] = make_uint2(lo, hi);
}

// Pass B (MFMA): Praw[hs][c] += sum_n wb[hs][n] * xb[n][c]
// Barrier-free: direct global->register fragments, no LDS.
template<int USE_XB>
__global__ __launch_bounds__(256, 3) void k_passB(const float* __restrict__ x,
    const unsigned short* __restrict__ xb, const unsigned short* __restrict__ wb,
    float* __restrict__ Praw) {
    int tid = threadIdx.x;
    // swizzle: all 8 c-tiles of one token-chunk land on one XCD (id mod 8 equal)
    int id = blockIdx.x;
    int r8 = id & 7, k8 = id >> 3;           // grid = 832
    int cb = k8 & 7;
    int tch = r8 + 8 * (k8 >> 3);
    if (tch >= 98) return;
    int c0 = cb * 128;
    int lane = tid & 63, wv = tid >> 6;
    int q = lane >> 4, mn = lane & 15;
    int cA = c0 + wv * 32 + mn;              // nt=0 col; nt=1 col = cA+16

    f32x4 acc[5][2];
    #pragma unroll
    for (int mt = 0; mt < 5; ++mt)
        #pragma unroll
        for (int nt = 0; nt < 2; ++nt) acc[mt][nt] = (f32x4){0.f, 0.f, 0.f, 0.f};

    const unsigned short* wrow = wb + (size_t)mn * NTOK + q * 8;
    bool arow_ok[5];
    #pragma unroll
    for (int mt = 0; mt < 5; ++mt) arow_ok[mt] = (mt * 16 + mn) < HSN;
    const short8 z8 = {0, 0, 0, 0, 0, 0, 0, 0};

    for (int scn = 0; scn < 16; ++scn) {
        int n0 = tch * 1024 + scn * 64;
        #pragma unroll
        for (int ks = 0; ks < 2; ++ks) {
            // NTOK % 32 == 0 -> each 32-token span is all-valid or all-OOB
            if (n0 + ks * 32 >= NTOK) continue;   // skipping adds exact zeros
            short8 a[5];
            #pragma unroll
            for (int mt = 0; mt < 5; ++mt)
                a[mt] = arow_ok[mt] ? *(const short8*)(wrow + (size_t)mt * 16 * NTOK + n0 + ks * 32)
                                    : z8;
            int tokb = n0 + ks * 32 + q * 8;
            S8u p0, p1;
            #pragma unroll
            for (int j = 0; j < 8; ++j) {
                if (USE_XB) {
                    p0.u[j] = xb[(size_t)(tokb + j) * C + cA];
                    p1.u[j] = xb[(size_t)(tokb + j) * C + cA + 16];
                } else {
                    p0.u[j] = f2bf(sanitize_f(x[(size_t)(tokb + j) * C + cA]));
                    p1.u[j] = f2bf(sanitize_f(x[(size_t)(tokb + j) * C + cA + 16]));
                }
            }
            #pragma unroll
            for (int mt = 0; mt < 5; ++mt) {
                acc[mt][0] = __builtin_amdgcn_mfma_f32_16x16x32_bf16(a[mt], p0.v, acc[mt][0], 0, 0, 0);
                acc[mt][1] = __builtin_amdgcn_mfma_f32_16x16x32_bf16(a[mt], p1.v, acc[mt][1], 0, 0, 0);
            }
        }
    }
    #pragma unroll
    for (int mt = 0; mt < 5; ++mt) {
        #pragma unroll
        for (int r = 0; r < 4; ++r) {
            int hs = mt * 16 + q * 4 + r;
            if (hs < HSN) {
                #pragma unroll
                for (int nt = 0; nt < 2; ++nt) {
                    int cc = c0 + wv * 32 + nt * 16 + mn;
                    atomicAdd(Praw + (size_t)hs * C + cc, acc[mt][nt][r]);
                }
            }
        }
    }
}

// o[s][hd] = sum_c Wv[hd][c] * w_nkv[c] * P[hs][c] + bv[hd]   (denom folded into w')
__global__ void k_o(const float* __restrict__ Praw, const float* __restrict__ in_proj_w,
                    const float* __restrict__ in_proj_b, const float* __restrict__ w_nkv,
                    float* __restrict__ o) {
    int tid = threadIdx.x, wid = tid >> 6, lane = tid & 63;
    int out = blockIdx.x * 4 + wid;                  // < 18432
    int s = out >> 10, hd = out & 1023;
    int h = hd >> 8;
    int hs = h * SN + s;
    const float* Wv = in_proj_w + (size_t)2 * C * C + (size_t)hd * C;
    const float* P = Praw + (size_t)hs * C;
    float acc = 0.f;
    #pragma unroll
    for (int k = 0; k < 16; ++k) { int c = lane + 64 * k; acc = fmaf(Wv[c], w_nkv[c] * P[c], acc); }
    acc = waveSum(acc);
    if (lane == 0) o[(size_t)s * C + hd] = acc + in_proj_b[2 * C + hd];
}

__global__ void k_obar(const float* __restrict__ o, float* __restrict__ obar) {
    int c = blockIdx.x * 256 + threadIdx.x;
    float acc = 0.f;
    #pragma unroll
    for (int s = 0; s < SN; ++s) acc += o[(size_t)s * C + c];
    obar[c] = acc * (1.0f / (float)SN);
}

// ctx[j] = sanitize(obar·Wout[j] + bout[j])
__global__ void k_out(const float* __restrict__ obar, const float* __restrict__ Wout,
                      const float* __restrict__ bout, float* __restrict__ outp) {
    int tid = threadIdx.x, wid = tid >> 6, lane = tid & 63;
    int j = blockIdx.x * 4 + wid;                    // < 1024
    float acc = 0.f;
    #pragma unroll
    for (int k = 0; k < 16; ++k) { int c = lane + 64 * k; acc = fmaf(obar[c], Wout[(size_t)j * C + c], acc); }
    acc = waveSum(acc);
    if (lane == 0) outp[j] = sanitize_f(acc + bout[j]);
}

extern "C" void kernel_launch(void* const* d_in, const int* in_sizes, int n_in,
                              void* d_out, int out_size, void* d_ws, size_t ws_size,
                              hipStream_t stream) {
    (void)in_sizes; (void)n_in; (void)out_size;
    const float* x         = (const float*)d_in[0];
    const float* seeds     = (const float*)d_in[1];
    const float* w_nq      = (const float*)d_in[2];
    const float* w_nkv     = (const float*)d_in[3];
    const float* in_proj_w = (const float*)d_in[4];
    const float* in_proj_b = (const float*)d_in[5];
    const float* out_proj_w = (const float*)d_in[6];
    const float* out_proj_b = (const float*)d_in[7];
    float* outp = (float*)d_out;

    float* ws     = (float*)d_ws;
    float* q      = ws;                  // 18432
    float* qp     = ws + 18432;          // 18432
    unsigned short* Ub = (unsigned short*)(ws + 36864);  // 80*1024 bf16
    float* bsc    = ws + 110592;         // 128
    float* scale  = ws + 110976;         // 100352
    float* pm     = ws + 211328;         // 1152
    float* pd     = ws + 212480;         // 1152
    float* scores = ws + 213632;         // 7200000
    float* Praw   = ws + 7413632;        // 73728
    float* o      = ws + 7487360;        // 18432
    float* obar   = ws + 7505792;        // 1024
    unsigned short* wb = (unsigned short*)(ws + 7506816);   // 72*100000 bf16
    unsigned short* xb = (unsigned short*)(ws + 11110400);  // 100000*1024 bf16
    int useXb = (ws_size >= (size_t)249241600ull) ? 1 : 0;

    k_qnorm<<<SN, 256, 0, stream>>>(seeds, w_nq, q);
    k_qp<<<4608, 256, 0, stream>>>(q, in_proj_w, in_proj_b, qp);
    k_U<<<320, 256, 0, stream>>>(qp, in_proj_w, in_proj_b, w_nkv, Ub, bsc);
    k_passA<<<782, 256, 0, stream>>>(x, Ub, bsc, scale, scores, xb, useXb);
    k_stats1<<<dim3(16, HSN), 256, 0, stream>>>(scores, pm, pd);
    k_w<<<dim3(98, HSN), 256, 0, stream>>>(scores, pm, pd, scale, wb);
    hipMemsetAsync(Praw, 0, (size_t)HSN * C * sizeof(float), stream);
    if (useXb)
        k_passB<1><<<832, 256, 0, stream>>>(x, xb, wb, Praw);
    else
        k_passB<0><<<832, 256, 0, stream>>>(x, xb, wb, Praw);
    k_o<<<4608, 256, 0, stream>>>(Praw, in_proj_w, in_proj_b, w_nkv, o);
    k_obar<<<4, 256, 0, stream>>>(o, obar);
    k_out<<<256, 256, 0, stream>>>(obar, out_proj_w, out_proj_b, outp);
}

// Round 3
// 1018.842 us; speedup vs baseline: 1.1236x; 1.1236x over previous
//
#include <hip/hip_runtime.h>
#include <math.h>

#define NTOK 100000
#define C 1024
#define SN 18
#define H 4
#define DH 256
#define HSN 72
#define CLAMPV 10000.0f
#define EPSV 1e-8f

using short8 = __attribute__((ext_vector_type(8))) short;
using f32x4  = __attribute__((ext_vector_type(4))) float;

union S8u { unsigned short u[8]; short8 v; };

__device__ __forceinline__ float sanitize_f(float v) {
    if (isnan(v)) return 0.0f;
    return fminf(CLAMPV, fmaxf(-CLAMPV, v));
}
__device__ __forceinline__ unsigned short f2bf(float f) {
    unsigned int u = __float_as_uint(f);
    u = (u + 0x7FFFu + ((u >> 16) & 1u)) >> 16;
    return (unsigned short)u;
}
__device__ __forceinline__ float waveSum(float v) {
    #pragma unroll
    for (int o = 32; o > 0; o >>= 1) v += __shfl_down(v, o, 64);
    return v;
}
__device__ __forceinline__ float waveMax(float v) {
    #pragma unroll
    for (int o = 32; o > 0; o >>= 1) v = fmaxf(v, __shfl_down(v, o, 64));
    return v;
}
// barrier that does NOT drain vmcnt: LDS writes visible, global loads stay in flight
__device__ __forceinline__ void barrier_lds_only() {
    asm volatile("s_waitcnt lgkmcnt(0)" ::: "memory");
    __builtin_amdgcn_s_barrier();
}

// q = rmsnorm(seeds, w_nq); one block per seed row
__global__ void k_qnorm(const float* __restrict__ seeds, const float* __restrict__ w_nq,
                        float* __restrict__ q) {
    int row = blockIdx.x, tid = threadIdx.x;
    const float* src = seeds + (size_t)row * C;
    float ss = 0.f;
    for (int c = tid; c < C; c += 256) { float v = sanitize_f(src[c]); ss += v * v; }
    __shared__ float red[4]; __shared__ float sSc;
    float w = waveSum(ss);
    if ((tid & 63) == 0) red[tid >> 6] = w;
    __syncthreads();
    if (tid == 0) {
        float t = red[0] + red[1] + red[2] + red[3];
        float rms = sqrtf(t / (float)C);
        sSc = 1.0f / (rms + EPSV);
    }
    __syncthreads();
    float sc = sSc;
    for (int c = tid; c < C; c += 256) q[(size_t)row * C + c] = w_nq[c] * sanitize_f(src[c]) * sc;
}

// qp[s][j] = (q[s]·Wq[j] + bq[j]) / sqrt(Dh); one wave per output
__global__ void k_qp(const float* __restrict__ q, const float* __restrict__ Wq,
                     const float* __restrict__ bq, float* __restrict__ qp) {
    int tid = threadIdx.x, wid = tid >> 6, lane = tid & 63;
    int out = blockIdx.x * 4 + wid;          // < 18432
    int s = out >> 10, j = out & 1023;
    const float* qrow = q + (size_t)s * C;
    const float* wrow = Wq + (size_t)j * C;
    float acc = 0.f;
    #pragma unroll
    for (int k = 0; k < 16; ++k) { int c = lane + 64 * k; acc = fmaf(qrow[c], wrow[c], acc); }
    acc = waveSum(acc);
    if (lane == 0) qp[out] = (acc + bq[j]) * 0.0625f;
}

// Ub[row][c] = bf16( (sum_d qp[s][h*DH+d] * Wk[h*DH+d][c]) * w_nkv[c] );  row = h*SN+s, rows 72..79 = 0
// bsc[row] (= qp[s,h,:]·bk[h,:]) folded in: computed by the ct==0 block of each row.
__global__ void k_U(const float* __restrict__ qp, const float* __restrict__ in_proj_w,
                    const float* __restrict__ in_proj_b, const float* __restrict__ w_nkv,
                    unsigned short* __restrict__ Ub, float* __restrict__ bsc) {
    int b = blockIdx.x, tid = threadIdx.x;
    int row = b >> 2, ct = b & 3;
    int c = ct * 256 + tid;
    __shared__ float qps[DH];
    __shared__ float red2[4];
    if (row < HSN) {
        int h = row / SN, s = row % SN;
        qps[tid] = qp[(size_t)s * C + h * DH + tid];
        __syncthreads();
        if (ct == 0) {                               // block-uniform branch
            float pb = qps[tid] * in_proj_b[C + h * DH + tid];
            float wsum = waveSum(pb);
            if ((tid & 63) == 0) red2[tid >> 6] = wsum;
            __syncthreads();
            if (tid == 0) bsc[row] = red2[0] + red2[1] + red2[2] + red2[3];
        }
        const float* Wk = in_proj_w + (size_t)C * C;
        float acc = 0.f;
        #pragma unroll 4
        for (int d = 0; d < DH; ++d) acc = fmaf(qps[d], Wk[(size_t)(h * DH + d) * C + c], acc);
        Ub[(size_t)row * C + c] = f2bf(acc * w_nkv[c]);
    } else {
        Ub[(size_t)row * C + c] = 0;
    }
}

// Pass A (MFMA): scores[hs][n] = scale_n * (U[hs]·x_san[n]) + bsc[hs]
// Round-1 staged layout + T14 pipeline: double-buffered LDS, loads issued one
// k-step ahead, barriers never drain vmcnt.
__global__ __launch_bounds__(256, 3) void k_passA(const float* __restrict__ x,
    const unsigned short* __restrict__ Ub, const float* __restrict__ bsc,
    float* __restrict__ scaleG, float* __restrict__ scoresG,
    unsigned short* __restrict__ xbG, int writeXb) {
    __shared__ unsigned short xbL[2][8192];   // [buf][ks2][tok128][c32]
    __shared__ unsigned short UbL[2][5120];   // [buf][ks2][hs80][c32]
    __shared__ float bscLds[HSN];
    __shared__ float scaleLds[128];
    int tid = threadIdx.x;
    int n0 = blockIdx.x * 128;
    if (tid < HSN) bscLds[tid] = bsc[tid];
    int lane = tid & 63, wv = tid >> 6;
    int q = lane >> 4, mn = lane & 15;

    // staging coords (x): thread covers tokens tokT+16i, float4 chunk cq
    int tokT = tid >> 4, cq = tid & 15;
    int ksq = cq >> 3, c32 = (cq & 7) * 4;

    f32x4 acc[5][2];
    #pragma unroll
    for (int mt = 0; mt < 5; ++mt)
        #pragma unroll
        for (int nt = 0; nt < 2; ++nt) acc[mt][nt] = (f32x4){0.f, 0.f, 0.f, 0.f};
    float ss[8];
    #pragma unroll
    for (int i = 0; i < 8; ++i) ss[i] = 0.f;

    float4 xr[8];
    uint2  ur[5];

    auto ISSUE = [&](int kt) {
        #pragma unroll
        for (int i = 0; i < 8; ++i) {
            int n = n0 + tokT + 16 * i;
            float4 v = make_float4(0.f, 0.f, 0.f, 0.f);
            if (n < NTOK) v = *(const float4*)(x + (size_t)n * C + kt * 64 + 4 * cq);
            xr[i] = v;
        }
        #pragma unroll
        for (int u = 0; u < 5; ++u) {
            int idx = tid + 256 * u;              // 0..1279
            int row = idx >> 4, cq2 = idx & 15;   // rows 0..79 always valid
            ur[u] = *(const uint2*)(Ub + (size_t)row * C + kt * 64 + 4 * cq2);
        }
    };
    auto COMMIT = [&](int buf, int kt) {
        #pragma unroll
        for (int i = 0; i < 8; ++i) {
            int n = n0 + tokT + 16 * i;
            float4 v = xr[i];
            v.x = sanitize_f(v.x); v.y = sanitize_f(v.y);
            v.z = sanitize_f(v.z); v.w = sanitize_f(v.w);
            ss[i] += v.x * v.x + v.y * v.y + v.z * v.z + v.w * v.w;
            unsigned int lo = (unsigned int)f2bf(v.x) | ((unsigned int)f2bf(v.y) << 16);
            unsigned int hi = (unsigned int)f2bf(v.z) | ((unsigned int)f2bf(v.w) << 16);
            if (writeXb && n < NTOK)
                *(uint2*)&xbG[(size_t)n * C + kt * 64 + 4 * cq] = make_uint2(lo, hi);
            *(uint2*)&xbL[buf][ksq * 4096 + (tokT + 16 * i) * 32 + c32] = make_uint2(lo, hi);
        }
        #pragma unroll
        for (int u = 0; u < 5; ++u) {
            int idx = tid + 256 * u;
            int row = idx >> 4, cq2 = idx & 15;
            *(uint2*)&UbL[buf][(cq2 >> 3) * 2560 + row * 32 + (cq2 & 7) * 4] = ur[u];
        }
    };

    ISSUE(0);
    #pragma unroll 2
    for (int kt = 0; kt < 16; ++kt) {
        int buf = kt & 1;
        COMMIT(buf, kt);
        if (kt < 15) ISSUE(kt + 1);               // loads stay in flight across barrier
        barrier_lds_only();
        #pragma unroll
        for (int ks = 0; ks < 2; ++ks) {
            short8 a[5], b[2];
            #pragma unroll
            for (int mt = 0; mt < 5; ++mt)
                a[mt] = *(const short8*)&UbL[buf][ks * 2560 + (mt * 16 + mn) * 32 + q * 8];
            #pragma unroll
            for (int nt = 0; nt < 2; ++nt)
                b[nt] = *(const short8*)&xbL[buf][ks * 4096 + (wv * 32 + nt * 16 + mn) * 32 + q * 8];
            #pragma unroll
            for (int mt = 0; mt < 5; ++mt)
                #pragma unroll
                for (int nt = 0; nt < 2; ++nt)
                    acc[mt][nt] = __builtin_amdgcn_mfma_f32_16x16x32_bf16(a[mt], b[nt], acc[mt][nt], 0, 0, 0);
        }
    }
    __syncthreads();
    // sumsq reduce: thread holds partial for token tokT+16i
    float* ssS = (float*)&xbL[0][0];              // 128*17 floats = 8704 B, fits
    #pragma unroll
    for (int i = 0; i < 8; ++i) ssS[(tokT + 16 * i) * 17 + cq] = ss[i];
    __syncthreads();
    if (tid < 128) {
        float t = 0.f;
        #pragma unroll
        for (int k = 0; k < 16; ++k) t += ssS[tid * 17 + k];
        float rms = sqrtf(t / (float)C);
        float sc = 1.0f / (rms + EPSV);
        scaleLds[tid] = sc;
        if (n0 + tid < NTOK) scaleG[n0 + tid] = sc;
    }
    __syncthreads();
    #pragma unroll
    for (int mt = 0; mt < 5; ++mt) {
        #pragma unroll
        for (int nt = 0; nt < 2; ++nt) {
            int tl = wv * 32 + nt * 16 + mn;
            int n = n0 + tl;
            #pragma unroll
            for (int r = 0; r < 4; ++r) {
                int hs = mt * 16 + q * 4 + r;
                if (hs < HSN && n < NTOK)
                    scoresG[(size_t)hs * NTOK + n] = acc[mt][nt][r] * scaleLds[tl] + bscLds[hs];
            }
        }
    }
}

// softmax stats stage 1: per (hs, chunk-of-6272): partial max + partial sum-exp (float4)
__global__ void k_stats1(const float* __restrict__ scoresG, float* __restrict__ pm,
                         float* __restrict__ pd) {
    int ch = blockIdx.x, hs = blockIdx.y, tid = threadIdx.x;
    int nbeg = ch * 6272, nend = nbeg + 6272;
    if (nend > NTOK) nend = NTOK;
    const float* row = scoresG + (size_t)hs * NTOK;
    float m = -INFINITY;
    for (int n = nbeg + 4 * tid; n < nend; n += 1024) {
        float4 v = *(const float4*)(row + n);
        m = fmaxf(fmaxf(m, fmaxf(v.x, v.y)), fmaxf(v.z, v.w));
    }
    __shared__ float red[4]; __shared__ float sM;
    float w = waveMax(m);
    if ((tid & 63) == 0) red[tid >> 6] = w;
    __syncthreads();
    if (tid == 0) sM = fmaxf(fmaxf(red[0], red[1]), fmaxf(red[2], red[3]));
    __syncthreads();
    float mm = sM;
    float sum = 0.f;
    for (int n = nbeg + 4 * tid; n < nend; n += 1024) {
        float4 v = *(const float4*)(row + n);
        sum += __expf(v.x - mm) + __expf(v.y - mm) + __expf(v.z - mm) + __expf(v.w - mm);
    }
    __syncthreads();
    float ws2 = waveSum(sum);
    if ((tid & 63) == 0) red[tid >> 6] = ws2;
    __syncthreads();
    if (tid == 0) { pm[hs * 16 + ch] = mm; pd[hs * 16 + ch] = red[0] + red[1] + red[2] + red[3]; }
}

// w-precompute (stats stage 2 folded): wb[hs][n] = bf16( exp(s-m)*scale_n/den )
__global__ void k_w(const float* __restrict__ scoresG, const float* __restrict__ pm,
                    const float* __restrict__ pd, const float* __restrict__ scaleG,
                    unsigned short* __restrict__ wb) {
    int hs = blockIdx.y;
    __shared__ float sM, sI;
    if (threadIdx.x == 0) {
        float m = -INFINITY;
        #pragma unroll
        for (int i = 0; i < 16; ++i) m = fmaxf(m, pm[hs * 16 + i]);
        float s = 0.f;
        #pragma unroll
        for (int i = 0; i < 16; ++i) s += pd[hs * 16 + i] * __expf(pm[hs * 16 + i] - m);
        sM = m; sI = 1.0f / s;
    }
    __syncthreads();
    int n = (blockIdx.x * 256 + threadIdx.x) * 4;
    if (n >= NTOK) return;
    float mh = sM, ih = sI;
    float4 s4 = *(const float4*)(scoresG + (size_t)hs * NTOK + n);
    float4 c4 = *(const float4*)(scaleG + n);
    unsigned int lo = (unsigned int)f2bf(__expf(s4.x - mh) * c4.x * ih)
                    | ((unsigned int)f2bf(__expf(s4.y - mh) * c4.y * ih) << 16);
    unsigned int hi = (unsigned int)f2bf(__expf(s4.z - mh) * c4.z * ih)
                    | ((unsigned int)f2bf(__expf(s4.w - mh) * c4.w * ih) << 16);
    *(uint2*)&wb[(size_t)hs * NTOK + n] = make_uint2(lo, hi);
}

// Pass B (MFMA): Praw[hs][c] += sum_n wb[hs][n] * xb[n][c]
// Round-1 staged layout + T14 pipeline (same discipline as passA).
template<int USE_XB>
__global__ __launch_bounds__(256, 3) void k_passB(const float* __restrict__ x,
    const unsigned short* __restrict__ xb, const unsigned short* __restrict__ wb,
    float* __restrict__ Praw) {
    __shared__ unsigned short xbTL[2][8192];   // [buf][ks2][c128][tok32]
    __shared__ unsigned short wTL[2][5120];    // [buf][ks2][hs80][tok32]
    int tid = threadIdx.x;
    // swizzle: all 8 c-tiles of one token-chunk land on one XCD (id mod 8 equal)
    int id = blockIdx.x;
    int r8 = id & 7, k8 = id >> 3;           // grid = 832
    int cb = k8 & 7;
    int tch = r8 + 8 * (k8 >> 3);
    if (tch >= 98) return;
    int c0 = cb * 128;
    int lane = tid & 63, wv = tid >> 6;
    int q = lane >> 4, mn = lane & 15;
    f32x4 acc[5][2];
    #pragma unroll
    for (int mt = 0; mt < 5; ++mt)
        #pragma unroll
        for (int nt = 0; nt < 2; ++nt) acc[mt][nt] = (f32x4){0.f, 0.f, 0.f, 0.f};

    // staging coords
    int half = tid >> 7, cL = tid & 127;     // x^T path
    uint2 wr[5];
    S8u  xg[4];

    auto ISSUE_B = [&](int scn) {
        int n0 = tch * 1024 + scn * 64;
        #pragma unroll
        for (int u = 0; u < 5; ++u) {
            int idx = tid + 256 * u;          // 0..1279
            int hsr = idx >> 4, tq = idx & 15;
            int nbase = n0 + 4 * tq;
            uint2 w4 = make_uint2(0u, 0u);
            if (hsr < HSN && nbase < NTOK)
                w4 = *(const uint2*)&wb[(size_t)hsr * NTOK + nbase];
            wr[u] = w4;
        }
        #pragma unroll
        for (int g = 0; g < 4; ++g) {
            int tok0 = 32 * half + 8 * g;
            #pragma unroll
            for (int j = 0; j < 8; ++j) {
                int n = n0 + tok0 + j;
                if (USE_XB) {
                    xg[g].u[j] = (n < NTOK) ? xb[(size_t)n * C + c0 + cL] : (unsigned short)0;
                } else {
                    float xv = 0.f;
                    if (n < NTOK) xv = x[(size_t)n * C + c0 + cL];
                    xg[g].u[j] = f2bf(sanitize_f(xv));
                }
            }
        }
    };
    auto COMMIT_B = [&](int buf) {
        #pragma unroll
        for (int u = 0; u < 5; ++u) {
            int idx = tid + 256 * u;
            int hsr = idx >> 4, tq = idx & 15;
            int ks = tq >> 3, t32 = (tq & 7) * 4;
            *(uint2*)&wTL[buf][ks * 2560 + hsr * 32 + t32] = wr[u];
        }
        #pragma unroll
        for (int g = 0; g < 4; ++g)
            *(short8*)&xbTL[buf][half * 4096 + cL * 32 + 8 * g] = xg[g].v;
    };

    ISSUE_B(0);
    #pragma unroll 2
    for (int scn = 0; scn < 16; ++scn) {
        int buf = scn & 1;
        COMMIT_B(buf);
        if (scn < 15) ISSUE_B(scn + 1);
        barrier_lds_only();
        #pragma unroll
        for (int ks = 0; ks < 2; ++ks) {
            short8 a[5], b[2];
            #pragma unroll
            for (int mt = 0; mt < 5; ++mt)
                a[mt] = *(const short8*)&wTL[buf][ks * 2560 + (mt * 16 + mn) * 32 + q * 8];
            #pragma unroll
            for (int nt = 0; nt < 2; ++nt)
                b[nt] = *(const short8*)&xbTL[buf][ks * 4096 + (wv * 32 + nt * 16 + mn) * 32 + q * 8];
            #pragma unroll
            for (int mt = 0; mt < 5; ++mt)
                #pragma unroll
                for (int nt = 0; nt < 2; ++nt)
                    acc[mt][nt] = __builtin_amdgcn_mfma_f32_16x16x32_bf16(a[mt], b[nt], acc[mt][nt], 0, 0, 0);
        }
    }
    #pragma unroll
    for (int mt = 0; mt < 5; ++mt) {
        #pragma unroll
        for (int r = 0; r < 4; ++r) {
            int hs = mt * 16 + q * 4 + r;
            if (hs < HSN) {
                #pragma unroll
                for (int nt = 0; nt < 2; ++nt) {
                    int cc = c0 + wv * 32 + nt * 16 + mn;
                    atomicAdd(Praw + (size_t)hs * C + cc, acc[mt][nt][r]);
                }
            }
        }
    }
}

// o[s][hd] = sum_c Wv[hd][c] * w_nkv[c] * P[hs][c] + bv[hd]   (denom folded into w')
__global__ void k_o(const float* __restrict__ Praw, const float* __restrict__ in_proj_w,
                    const float* __restrict__ in_proj_b, const float* __restrict__ w_nkv,
                    float* __restrict__ o) {
    int tid = threadIdx.x, wid = tid >> 6, lane = tid & 63;
    int out = blockIdx.x * 4 + wid;                  // < 18432
    int s = out >> 10, hd = out & 1023;
    int h = hd >> 8;
    int hs = h * SN + s;
    const float* Wv = in_proj_w + (size_t)2 * C * C + (size_t)hd * C;
    const float* P = Praw + (size_t)hs * C;
    float acc = 0.f;
    #pragma unroll
    for (int k = 0; k < 16; ++k) { int c = lane + 64 * k; acc = fmaf(Wv[c], w_nkv[c] * P[c], acc); }
    acc = waveSum(acc);
    if (lane == 0) o[(size_t)s * C + hd] = acc + in_proj_b[2 * C + hd];
}

__global__ void k_obar(const float* __restrict__ o, float* __restrict__ obar) {
    int c = blockIdx.x * 256 + threadIdx.x;
    float acc = 0.f;
    #pragma unroll
    for (int s = 0; s < SN; ++s) acc += o[(size_t)s * C + c];
    obar[c] = acc * (1.0f / (float)SN);
}

// ctx[j] = sanitize(obar·Wout[j] + bout[j])
__global__ void k_out(const float* __restrict__ obar, const float* __restrict__ Wout,
                      const float* __restrict__ bout, float* __restrict__ outp) {
    int tid = threadIdx.x, wid = tid >> 6, lane = tid & 63;
    int j = blockIdx.x * 4 + wid;                    // < 1024
    float acc = 0.f;
    #pragma unroll
    for (int k = 0; k < 16; ++k) { int c = lane + 64 * k; acc = fmaf(obar[c], Wout[(size_t)j * C + c], acc); }
    acc = waveSum(acc);
    if (lane == 0) outp[j] = sanitize_f(acc + bout[j]);
}

extern "C" void kernel_launch(void* const* d_in, const int* in_sizes, int n_in,
                              void* d_out, int out_size, void* d_ws, size_t ws_size,
                              hipStream_t stream) {
    (void)in_sizes; (void)n_in; (void)out_size;
    const float* x         = (const float*)d_in[0];
    const float* seeds     = (const float*)d_in[1];
    const float* w_nq      = (const float*)d_in[2];
    const float* w_nkv     = (const float*)d_in[3];
    const float* in_proj_w = (const float*)d_in[4];
    const float* in_proj_b = (const float*)d_in[5];
    const float* out_proj_w = (const float*)d_in[6];
    const float* out_proj_b = (const float*)d_in[7];
    float* outp = (float*)d_out;

    float* ws     = (float*)d_ws;
    float* q      = ws;                  // 18432
    float* qp     = ws + 18432;          // 18432
    unsigned short* Ub = (unsigned short*)(ws + 36864);  // 80*1024 bf16
    float* bsc    = ws + 110592;         // 128
    float* scale  = ws + 110976;         // 100352
    float* pm     = ws + 211328;         // 1152
    float* pd     = ws + 212480;         // 1152
    float* scores = ws + 213632;         // 7200000
    float* Praw   = ws + 7413632;        // 73728
    float* o      = ws + 7487360;        // 18432
    float* obar   = ws + 7505792;        // 1024
    unsigned short* wb = (unsigned short*)(ws + 7506816);   // 72*100000 bf16
    unsigned short* xb = (unsigned short*)(ws + 11110400);  // 100000*1024 bf16
    int useXb = (ws_size >= (size_t)249241600ull) ? 1 : 0;

    k_qnorm<<<SN, 256, 0, stream>>>(seeds, w_nq, q);
    k_qp<<<4608, 256, 0, stream>>>(q, in_proj_w, in_proj_b, qp);
    k_U<<<320, 256, 0, stream>>>(qp, in_proj_w, in_proj_b, w_nkv, Ub, bsc);
    k_passA<<<782, 256, 0, stream>>>(x, Ub, bsc, scale, scores, xb, useXb);
    k_stats1<<<dim3(16, HSN), 256, 0, stream>>>(scores, pm, pd);
    k_w<<<dim3(98, HSN), 256, 0, stream>>>(scores, pm, pd, scale, wb);
    hipMemsetAsync(Praw, 0, (size_t)HSN * C * sizeof(float), stream);
    if (useXb)
        k_passB<1><<<832, 256, 0, stream>>>(x, xb, wb, Praw);
    else
        k_passB<0><<<832, 256, 0, stream>>>(x, xb, wb, Praw);
    k_o<<<4608, 256, 0, stream>>>(Praw, in_proj_w, in_proj_b, w_nkv, o);
    k_obar<<<4, 256, 0, stream>>>(o, obar);
    k_out<<<256, 256, 0, stream>>>(obar, out_proj_w, out_proj_b, outp);
}